// Round 18
// baseline (295.384 us; speedup 1.0000x reference)
//
#include <hip/hip_runtime.h>
#include <hip/hip_bf16.h>

typedef __attribute__((ext_vector_type(8))) short short8;
typedef __attribute__((ext_vector_type(4))) int i32x4;

#define HW     3136      // 56*56
#define M_TOT  200704    // 64*3136
#define NSTEP  18        // K=1152 / 64 (half-tap per step)
#define NBLK   896       // conv grid = 64 n x 14 h-groups (224 m each)
#define SLABB  44544     // 6*58*128 slab bytes

__device__ __forceinline__ void gload_lds16(const void* g, void* l) {
    __builtin_amdgcn_global_load_lds(
        (const __attribute__((address_space(1))) void*)g,
        (__attribute__((address_space(3))) void*)l, 16, 0, 0);
}

// ---------------- weight prep: scales (blocks 0..255) + sign-pack (blocks 256..1407) ----
// wswz8 fragment order (i8): byte i = s*8192 + f*1024 + l*16 + e, e in [0,16)
//   (s = 64-k step = tap*2 + ks) cout = f*16 + (l&15); k = s*64 + (l>>4)*16 + e
__global__ __launch_bounds__(256) void wprep_kernel(const float* __restrict__ w1,
                                                    const float* __restrict__ w2,
                                                    float* __restrict__ scale1,
                                                    float* __restrict__ scale2,
                                                    char* __restrict__ ws1,
                                                    char* __restrict__ ws2) {
    int t = threadIdx.x;
    if (blockIdx.x < 256) {
        int o = blockIdx.x;
        const float* w = w1;
        float* scale = scale1;
        if (o >= 128) { o -= 128; w = w2; scale = scale2; }
        float s = 0.f;
        for (int i = t; i < 1152; i += 256) s += fabsf(w[o * 1152 + i]);
        __shared__ float r1[256];
        r1[t] = s; __syncthreads();
        for (int off = 128; off > 0; off >>= 1) {
            if (t < off) r1[t] += r1[t + off];
            __syncthreads();
        }
        if (t == 0) scale[o] = r1[0] * (1.f / 1152.f);
        return;
    }
    int i = (blockIdx.x - 256) * 256 + t;     // < 294912
    const float* w = w1;
    char* wsz = ws1;
    if (i >= 147456) { i -= 147456; w = w2; wsz = ws2; }
    int e = i & 15, l = (i >> 4) & 63, f = (i >> 10) & 7, s = i >> 13;
    int cout = f * 16 + (l & 15);
    int k = s * 64 + (l >> 4) * 16 + e;
    int tap = k >> 7, cin = k & 127;
    float v = w[(cout * 128 + cin) * 9 + tap];
    wsz[i] = v > 0.f ? (char)1 : (v < 0.f ? (char)-1 : (char)0);
}

// ---------------- BN1 stats (float4-vectorized loads) ----------------
__global__ __launch_bounds__(256) void stats_nchw_kernel(const float* __restrict__ x,
                                                         float* __restrict__ psum,
                                                         float* __restrict__ psq) {
    int bid = blockIdx.x;            // 8192: n = bid>>7, c = bid&127
    int n = bid >> 7, c = bid & 127;
    const float* p = x + (n * 128 + c) * HW;
    int t = threadIdx.x;
    float s = 0.f, q = 0.f;
    for (int i4 = t; i4 < 784; i4 += 256) {          // 3136 = 784*4
        float4 v = *(const float4*)(p + i4 * 4);
        s += v.x + v.y + v.z + v.w;
        q += v.x * v.x + v.y * v.y + v.z * v.z + v.w * v.w;
    }
    __shared__ float r1[256], r2[256];
    r1[t] = s; r2[t] = q; __syncthreads();
    for (int off = 128; off > 0; off >>= 1) {
        if (t < off) { r1[t] += r1[t + off]; r2[t] += r2[t + off]; }
        __syncthreads();
    }
    if (t == 0) { psum[c * 64 + n] = r1[0]; psq[c * 64 + n] = r2[0]; }
}

// reduce per-conv-block partials, block-major layout: psumB[blk*128 + c]
__global__ __launch_bounds__(256) void finalizeB_kernel(const float* __restrict__ psumB,
                                                        const float* __restrict__ psqB,
                                                        float* __restrict__ mean,
                                                        float* __restrict__ rstd) {
    int c = blockIdx.x, t = threadIdx.x;
    float s = 0.f, q = 0.f;
    for (int j = t; j < NBLK; j += 256) { s += psumB[j * 128 + c]; q += psqB[j * 128 + c]; }
    __shared__ float r1[256], r2[256];
    r1[t] = s; r2[t] = q; __syncthreads();
    for (int off = 128; off > 0; off >>= 1) {
        if (t < off) { r1[t] += r1[t + off]; r2[t] += r2[t + off]; }
        __syncthreads();
    }
    if (t == 0) {
        const float invN = 1.f / 200704.f;
        float m = r1[0] * invN;
        float var = r2[0] * invN - m * m;
        mean[c] = m;
        rstd[c] = 1.f / sqrtf(var + 1e-5f);
    }
}

// ---------------- act1: BN1 finalize (folded, bit-identical order) + sign -> NHWC i8 ----
__global__ __launch_bounds__(256) void act1_kernel(const float* __restrict__ x,
        const float* __restrict__ psum, const float* __restrict__ psq,
        const float* __restrict__ g, const float* __restrict__ b,
        char* __restrict__ apad) {
    __shared__ float row[128 * 57];
    __shared__ float smean[128], srstd[128];
    int blk = blockIdx.x;                 // 64*58
    int n = blk / 58, hp = blk - n * 58;
    char* o = apad + (n * 58 + hp) * 58 * 128;
    int t = threadIdx.x;
    if (hp == 0 || hp == 57) {
        for (int i4 = t; i4 < 58 * 32; i4 += 256)
            *(char4*)(o + i4 * 4) = make_char4(0, 0, 0, 0);
        return;
    }
    if (t < 128) {                        // same serial order as old finalize -> bit-identical
        float s = 0.f, q = 0.f;
        for (int j = 0; j < 64; ++j) { s += psum[t * 64 + j]; q += psq[t * 64 + j]; }
        const float invN = 1.f / 200704.f;
        float m = s * invN;
        float var = q * invN - m * m;
        smean[t] = m;
        srstd[t] = 1.f / sqrtf(var + 1e-5f);
    }
    const float* src = x + n * (128 * HW) + (hp - 1) * 56;
    for (int i4 = t; i4 < 128 * 14; i4 += 256) {      // float4 staging loads
        int c = i4 / 14, w4 = (i4 - c * 14) * 4;
        float4 v = *(const float4*)(src + c * HW + w4);
        row[c * 57 + w4 + 0] = v.x;
        row[c * 57 + w4 + 1] = v.y;
        row[c * 57 + w4 + 2] = v.z;
        row[c * 57 + w4 + 3] = v.w;
    }
    __syncthreads();
    for (int i4 = t; i4 < 58 * 32; i4 += 256) {       // char4 per thread
        int wp = i4 >> 5;
        int c0 = (i4 & 31) * 4;
        char q[4] = {0, 0, 0, 0};
        if (wp >= 1 && wp <= 56) {
#pragma unroll
            for (int k = 0; k < 4; ++k) {
                int c = c0 + k;
                float xn = (row[c * 57 + wp - 1] - smean[c]) * srstd[c] * g[c] + b[c];
                q[k] = xn > 0.f ? 1 : (xn < 0.f ? -1 : 0);
            }
        }
        *(char4*)(o + wp * 128 + c0) = make_char4(q[0], q[1], q[2], q[3]);
    }
}

__global__ __launch_bounds__(256) void act2_kernel(const short* __restrict__ p1,
        const float* __restrict__ scale1, const float* __restrict__ a1ptr,
        const float* __restrict__ mean, const float* __restrict__ rstd,
        const float* __restrict__ g, const float* __restrict__ b,
        char* __restrict__ apad) {
    __shared__ float row[128 * 57];
    int blk = blockIdx.x;
    int n = blk / 58, hp = blk - n * 58;
    char* o = apad + (n * 58 + hp) * 58 * 128;
    int t = threadIdx.x;
    if (hp == 0 || hp == 57) {
        for (int i4 = t; i4 < 58 * 32; i4 += 256)
            *(char4*)(o + i4 * 4) = make_char4(0, 0, 0, 0);
        return;
    }
    float a1 = a1ptr[0];
    const short* src = p1 + n * HW + (hp - 1) * 56;   // + c*M_TOT + w
    for (int i8 = t; i8 < 128 * 7; i8 += 256) {       // short8 staging loads
        int c = i8 / 7, w8 = (i8 - c * 7) * 8;
        short8 v = *(const short8*)(src + (size_t)c * M_TOT + w8);
        float sc = scale1[c];
#pragma unroll
        for (int k = 0; k < 8; ++k) {
            float val = sc * (float)v[k];
            row[c * 57 + w8 + k] = val >= 0.f ? val : a1 * val;   // prelu1
        }
    }
    __syncthreads();
    for (int i4 = t; i4 < 58 * 32; i4 += 256) {
        int wp = i4 >> 5;
        int c0 = (i4 & 31) * 4;
        char q[4] = {0, 0, 0, 0};
        if (wp >= 1 && wp <= 56) {
#pragma unroll
            for (int k = 0; k < 4; ++k) {
                int c = c0 + k;
                float xn = (row[c * 57 + wp - 1] - mean[c]) * rstd[c] * g[c] + b[c];
                q[k] = xn > 0.f ? 1 : (xn < 0.f ? -1 : 0);
            }
        }
        *(char4*)(o + wp * 128 + c0) = make_char4(q[0], q[1], q[2], q[3]);
    }
}

// ---------------- implicit-GEMM binary conv, i8 MFMA, 3-blocks/CU variant ----------------
// Slab-resident B (staged once, XOR-swizzled). A: SINGLE 8KB half-tap buffer, 18 serial
// steps (stage -> drain -> barrier -> compute). LDS = 52.5KB -> 3 blocks/CU = 12 waves:
// cross-block overlap hides the serial A-stage latency (m114) instead of intra-block
// pipelining (r13 showed lookahead at 2 blocks/CU buys nothing past 48us).
// Numerically identical to r17: same per-acc MFMA order (s = tap*2+ks), same stats.
template<bool RAW, typename OutT>
__global__ __launch_bounds__(256, 3) void conv_kernel(
        const char* __restrict__ apad,
        const char* __restrict__ wswz,
        const float* __restrict__ scale,
        const float* __restrict__ aptr,
        OutT* __restrict__ obuf,
        float* __restrict__ psumB,
        float* __restrict__ psqB) {
    // layout: slab [0, 44544) ; A 1-buf [44544, +8192) ; stats [52736, +2048) = 54784
    __shared__ __align__(1024) char lds[SLABB + 8192 + 2048];

    const int tid = threadIdx.x;
    const int lane = tid & 63;
    const int wid = tid >> 6;
    const int l15 = lane & 15;
    const int lq = lane >> 4;
    const int wr = wid >> 1;  // cout half
    const int wc = wid & 1;   // m half (112 m each)

    int bid = blockIdx.x;
    int mblk = (bid & 7) * 112 + (bid >> 3);   // XCD-contiguous (896 = 8*112)
    const int n = mblk / 14;
    const int hg = mblk - n * 14;
    const int m0 = n * HW + hg * 224;          // block's first output m

    const char* slabsrc = apad + (size_t)(n * 58 + hg * 4) * 58 * 128;
    char* slab = lds;
    char* Abuf = lds + SLABB;

    // ---- stage slab once: 11 instrs/thread, within-row XOR pre-swizzle (rule #21) ----
    {
#pragma unroll
        for (int i = 0; i < 11; ++i) {
            int gbyte = i * 4096 + tid * 16;
            if (i < 10 || gbyte < SLABB) {
                int r = gbyte >> 7;
                int cp = (gbyte >> 4) & 7;
                int wp = r % 58;
                gload_lds16(slabsrc + (gbyte & ~127) + ((cp ^ (wp & 7)) << 4),
                            slab + i * 4096 + wid * 1024);
            }
        }
    }

    // per-lane B-frag constants: mloc = wc*112 + mi*16 + l15 -> (ho, w)
    int Pm[7], Wm[7];
#pragma unroll
    for (int mi = 0; mi < 7; ++mi) {
        int mloc = wc * 112 + mi * 16 + l15;
        int ho = mloc / 56;
        int w = mloc - ho * 56;
        Pm[mi] = (ho * 58 + w) * 128;   // slab row base for dh=dw=0
        Wm[mi] = w;
    }

    i32x4 acc[4][7];
#pragma unroll
    for (int i = 0; i < 4; ++i)
#pragma unroll
        for (int j = 0; j < 7; ++j)
            acc[i][j] = (i32x4){0, 0, 0, 0};

    for (int s = 0; s < NSTEP; ++s) {
        // stage half-tap s (8KB): 2 gloads/thread, then drain + barrier (serial A-path;
        // latency hidden by the other 2 blocks on this CU)
        const char* wsrc = wswz + s * 8192 + tid * 16;
        gload_lds16(wsrc,        Abuf + wid * 1024);
        gload_lds16(wsrc + 4096, Abuf + 4096 + wid * 1024);
        asm volatile("s_waitcnt vmcnt(0)" ::: "memory");
        __builtin_amdgcn_s_barrier();

        int tap = s >> 1;
        int dh = tap / 3;
        int dw = tap - dh * 3;
        int Q = (dh * 58 + dw) * 128;          // slab row offset for this tap
        int c16 = (s & 1) * 4 + lq;            // per-lane k chunk

        i32x4 af[4], bf[7];
#pragma unroll
        for (int ci = 0; ci < 4; ++ci)
            af[ci] = *(const i32x4*)(Abuf + (wr * 4 + ci) * 1024 + lane * 16);
#pragma unroll
        for (int mi = 0; mi < 7; ++mi) {
            int wxd = (Wm[mi] + dw) & 7;
            bf[mi] = *(const i32x4*)(slab + Pm[mi] + Q + ((c16 ^ wxd) << 4));
        }
        __builtin_amdgcn_s_setprio(1);
#pragma unroll
        for (int ci = 0; ci < 4; ++ci)
#pragma unroll
            for (int mi = 0; mi < 7; ++mi)
                acc[ci][mi] = __builtin_amdgcn_mfma_i32_16x16x64_i8(
                    af[ci], bf[mi], acc[ci][mi], 0, 0, 0);
        __builtin_amdgcn_s_setprio(0);
        __builtin_amdgcn_s_barrier();          // all reads of Abuf done before next stage
    }

    // ---- epilogue: store + fused per-channel stats of prelu(scale*acc) ----
    float alpha = aptr[0];
    float* partS = (float*)(lds + SLABB + 8192);   // dedicated 2KB stats scratch
    float* partQ = (float*)(lds + SLABB + 8192 + 1024);
#pragma unroll
    for (int ci = 0; ci < 4; ++ci) {
        int cb = wr * 64 + ci * 16 + lq * 4;
#pragma unroll
        for (int r = 0; r < 4; ++r) {
            float sc = scale[cb + r];
            OutT* op = obuf + (size_t)(cb + r) * M_TOT + m0 + wc * 112 + l15;
            float s = 0.f, q = 0.f;
#pragma unroll
            for (int mi = 0; mi < 7; ++mi) {
                int iv = acc[ci][mi][r];
                float v = (float)iv * sc;
                float pv = v >= 0.f ? v : alpha * v;
                if constexpr (RAW) op[mi * 16] = (OutT)(short)iv;
                else               op[mi * 16] = (OutT)__float2bfloat16(pv);
                s += pv; q += pv * pv;
            }
#pragma unroll
            for (int msk = 1; msk <= 8; msk <<= 1) {
                s += __shfl_xor(s, msk, 64);
                q += __shfl_xor(q, msk, 64);
            }
            if (l15 == 0) { partS[wc * 128 + cb + r] = s; partQ[wc * 128 + cb + r] = q; }
        }
    }
    __syncthreads();
    if (tid < 128) {
        psumB[bid * 128 + tid] = partS[tid] + partS[128 + tid];   // coalesced row
        psqB [bid * 128 + tid] = partQ[tid] + partQ[128 + tid];
    }
}

// ---------------- final: BN3(prelu2'd bf16 input) + residual + prelu3 ----------------
__global__ __launch_bounds__(256) void final_kernel(const __hip_bfloat16* __restrict__ p2,
        const float* __restrict__ x,
        const float* __restrict__ mean, const float* __restrict__ rstd,
        const float* __restrict__ g, const float* __restrict__ b,
        const float* __restrict__ a3ptr, float* __restrict__ out) {
    int bid = blockIdx.x;               // 8192
    int n = bid >> 7, c = bid & 127;
    float m = mean[c], r = rstd[c], gg = g[c], bb = b[c], a3 = a3ptr[0];
    const __hip_bfloat16* pp = p2 + (size_t)c * M_TOT + n * HW;
    const float* xx = x + (n * 128 + c) * HW;
    float* oo = out + (n * 128 + c) * HW;
    int t = threadIdx.x;
    for (int i8 = t; i8 < 392; i8 += 256) {     // 3136 = 392*8
        short8 v = *(const short8*)(pp + i8 * 8);
        float4 x0 = *(const float4*)(xx + i8 * 8);
        float4 x1 = *(const float4*)(xx + i8 * 8 + 4);
        float o[8];
#pragma unroll
        for (int k = 0; k < 8; ++k) {
            float pv = __uint_as_float(((unsigned int)(unsigned short)v[k]) << 16);
            float xv = (k < 4) ? ((const float*)&x0)[k] : ((const float*)&x1)[k - 4];
            float val = (pv - m) * r * gg + bb + xv;
            o[k] = val >= 0.f ? val : a3 * val; // prelu3
        }
        *(float4*)(oo + i8 * 8)     = make_float4(o[0], o[1], o[2], o[3]);
        *(float4*)(oo + i8 * 8 + 4) = make_float4(o[4], o[5], o[6], o[7]);
    }
}

extern "C" void kernel_launch(void* const* d_in, const int* in_sizes, int n_in,
                              void* d_out, int out_size, void* d_ws, size_t ws_size,
                              hipStream_t stream) {
    const float* x  = (const float*)d_in[0];
    const float* g1 = (const float*)d_in[1];
    const float* b1 = (const float*)d_in[2];
    const float* w1 = (const float*)d_in[3];
    const float* a1 = (const float*)d_in[4];
    const float* g2 = (const float*)d_in[5];
    const float* b2 = (const float*)d_in[6];
    const float* w2 = (const float*)d_in[7];
    const float* a2 = (const float*)d_in[8];
    const float* g3 = (const float*)d_in[9];
    const float* b3 = (const float*)d_in[10];
    const float* a3 = (const float*)d_in[11];
    float* out = (float*)d_out;
    char* ws = (char*)d_ws;

    // Workspace map — end offsets computed as start + exact size:
    //   psum   4,096   + 32,768   = 36,864
    //   psq    36,864  + 32,768   = 69,632
    //   psumB  69,632  + 802,816  = 872,448      (region >= 896*128*4 = 458,752)
    //   psqB   872,448 + 802,816  = 1,675,264
    //   wswz1  1,675,264 + 147,456 = 1,822,720
    //   wswz2  1,822,720 + 147,456 = 1,970,176
    //   apad8  1,970,176 + 27,557,888 = 29,528,064   (64*58*58*128 bytes)
    //   buf2b  29,528,064 + 25,690,112 = 55,218,176  (bf16, 128*200704*2)
    float* scale1 = (float*)(ws);
    float* scale2 = (float*)(ws + 512);
    float* mean2  = (float*)(ws + 2048);
    float* rstd2  = (float*)(ws + 2560);
    float* mean3  = (float*)(ws + 3072);
    float* rstd3  = (float*)(ws + 3584);
    float* psum   = (float*)(ws + 4096);
    float* psq    = (float*)(ws + 36864);
    float* psumB  = (float*)(ws + 69632);
    float* psqB   = (float*)(ws + 872448);
    char* wswz1   = (char*)(ws + 1675264);
    char* wswz2   = (char*)(ws + 1822720);
    char* apad8   = (char*)(ws + 1970176);
    __hip_bfloat16* buf2b = (__hip_bfloat16*)(ws + 29528064);
    short* buf1s  = (short*)out;              // alias d_out (51.4 of 103 MB)

    wprep_kernel<<<1408, 256, 0, stream>>>(w1, w2, scale1, scale2, wswz1, wswz2);

    stats_nchw_kernel<<<8192, 256, 0, stream>>>(x, psum, psq);
    act1_kernel<<<3712, 256, 0, stream>>>(x, psum, psq, g1, b1, apad8);
    conv_kernel<true, short><<<NBLK, 256, 0, stream>>>(apad8, wswz1, scale1, a1,
                                                       buf1s, psumB, psqB);

    finalizeB_kernel<<<128, 256, 0, stream>>>(psumB, psqB, mean2, rstd2);
    act2_kernel<<<3712, 256, 0, stream>>>(buf1s, scale1, a1, mean2, rstd2, g2, b2, apad8);
    conv_kernel<false, __hip_bfloat16><<<NBLK, 256, 0, stream>>>(apad8, wswz2, scale2, a2,
                                                                 buf2b, psumB, psqB);

    finalizeB_kernel<<<128, 256, 0, stream>>>(psumB, psqB, mean3, rstd3);
    final_kernel<<<8192, 256, 0, stream>>>(buf2b, x, mean3, rstd3, g3, b3, a3, out);
}

// Round 19
// 240.147 us; speedup vs baseline: 1.2300x; 1.2300x over previous
//
#include <hip/hip_runtime.h>
#include <hip/hip_bf16.h>

typedef __attribute__((ext_vector_type(8))) short short8;
typedef __attribute__((ext_vector_type(4))) int i32x4;

#define HW     3136      // 56*56
#define M_TOT  200704    // 64*3136
#define NTAP   9         // K=1152 / 128 (one 3x3 tap per step)
#define NBLK   896       // conv grid = 64 n x 14 h-groups (224 m each)
#define SLABB  44544     // 6*58*128 slab bytes

__device__ __forceinline__ void gload_lds16(const void* g, void* l) {
    __builtin_amdgcn_global_load_lds(
        (const __attribute__((address_space(1))) void*)g,
        (__attribute__((address_space(3))) void*)l, 16, 0, 0);
}

// ---------------- weight prep ----------------
// wswz8 fragment order (i8): byte i = s*8192 + f*1024 + l*16 + e, e in [0,16)
//   (s = 64-k step = tap*2 + ks) cout = f*16 + (l&15); k = s*64 + (l>>4)*16 + e
__global__ __launch_bounds__(256) void wsign_kernel(const float* __restrict__ w1,
                                                    const float* __restrict__ w2,
                                                    char* __restrict__ ws1,
                                                    char* __restrict__ ws2) {
    int i = blockIdx.x * 256 + threadIdx.x;   // < 294912
    const float* w = w1;
    char* wsz = ws1;
    if (i >= 147456) { i -= 147456; w = w2; wsz = ws2; }
    int e = i & 15, l = (i >> 4) & 63, f = (i >> 10) & 7, s = i >> 13;
    int cout = f * 16 + (l & 15);
    int k = s * 64 + (l >> 4) * 16 + e;
    int tap = k >> 7, cin = k & 127;
    float v = w[(cout * 128 + cin) * 9 + tap];
    wsz[i] = v > 0.f ? (char)1 : (v < 0.f ? (char)-1 : (char)0);
}

__global__ __launch_bounds__(256) void wscale_kernel(const float* __restrict__ w1,
                                                     const float* __restrict__ w2,
                                                     float* __restrict__ scale1,
                                                     float* __restrict__ scale2) {
    int o = blockIdx.x;                 // 256: 0..127 -> w1, 128..255 -> w2
    const float* w = w1;
    float* scale = scale1;
    if (o >= 128) { o -= 128; w = w2; scale = scale2; }
    int t = threadIdx.x;
    float s = 0.f;
    for (int i = t; i < 1152; i += 256) s += fabsf(w[o * 1152 + i]);
    __shared__ float r1[256];
    r1[t] = s; __syncthreads();
    for (int off = 128; off > 0; off >>= 1) {
        if (t < off) r1[t] += r1[t + off];
        __syncthreads();
    }
    if (t == 0) scale[o] = r1[0] * (1.f / 1152.f);
}

// ---------------- BN1 stats (float4-vectorized loads, G13) ----------------
__global__ __launch_bounds__(256) void stats_nchw_kernel(const float* __restrict__ x,
                                                         float* __restrict__ psum,
                                                         float* __restrict__ psq) {
    int bid = blockIdx.x;            // 8192: n = bid>>7, c = bid&127
    int n = bid >> 7, c = bid & 127;
    const float* p = x + (n * 128 + c) * HW;
    int t = threadIdx.x;
    float s = 0.f, q = 0.f;
    for (int i4 = t; i4 < 784; i4 += 256) {          // 3136 = 784*4
        float4 v = *(const float4*)(p + i4 * 4);
        s += v.x + v.y + v.z + v.w;
        q += v.x * v.x + v.y * v.y + v.z * v.z + v.w * v.w;
    }
    __shared__ float r1[256], r2[256];
    r1[t] = s; r2[t] = q; __syncthreads();
    for (int off = 128; off > 0; off >>= 1) {
        if (t < off) { r1[t] += r1[t + off]; r2[t] += r2[t + off]; }
        __syncthreads();
    }
    if (t == 0) { psum[c * 64 + n] = r1[0]; psq[c * 64 + n] = r2[0]; }
}

__global__ void finalize_kernel(const float* __restrict__ psum, const float* __restrict__ psq,
                                int P, float* __restrict__ mean, float* __restrict__ rstd) {
    int c = threadIdx.x;
    if (c >= 128) return;
    float s = 0.f, q = 0.f;
    for (int j = 0; j < P; ++j) { s += psum[c * P + j]; q += psq[c * P + j]; }
    const float invN = 1.f / 200704.f;
    float m = s * invN;
    float var = q * invN - m * m;
    mean[c] = m;
    rstd[c] = 1.f / sqrtf(var + 1e-5f);
}

// reduce per-conv-block partials, block-major layout: psumB[blk*128 + c]
__global__ __launch_bounds__(256) void finalizeB_kernel(const float* __restrict__ psumB,
                                                        const float* __restrict__ psqB,
                                                        float* __restrict__ mean,
                                                        float* __restrict__ rstd) {
    int c = blockIdx.x, t = threadIdx.x;
    float s = 0.f, q = 0.f;
    for (int j = t; j < NBLK; j += 256) { s += psumB[j * 128 + c]; q += psqB[j * 128 + c]; }
    __shared__ float r1[256], r2[256];
    r1[t] = s; r2[t] = q; __syncthreads();
    for (int off = 128; off > 0; off >>= 1) {
        if (t < off) { r1[t] += r1[t + off]; r2[t] += r2[t + off]; }
        __syncthreads();
    }
    if (t == 0) {
        const float invN = 1.f / 200704.f;
        float m = r1[0] * invN;
        float var = r2[0] * invN - m * m;
        mean[c] = m;
        rstd[c] = 1.f / sqrtf(var + 1e-5f);
    }
}

// ---------------- normalize + sign -> padded NHWC i8 ----------------
__global__ __launch_bounds__(256) void act1_kernel(const float* __restrict__ x,
        const float* __restrict__ mean, const float* __restrict__ rstd,
        const float* __restrict__ g, const float* __restrict__ b,
        char* __restrict__ apad) {
    __shared__ float row[128 * 57];
    int blk = blockIdx.x;                 // 64*58
    int n = blk / 58, hp = blk - n * 58;
    char* o = apad + (n * 58 + hp) * 58 * 128;
    int t = threadIdx.x;
    if (hp == 0 || hp == 57) {
        for (int i4 = t; i4 < 58 * 32; i4 += 256)
            *(char4*)(o + i4 * 4) = make_char4(0, 0, 0, 0);
        return;
    }
    const float* src = x + n * (128 * HW) + (hp - 1) * 56;
    for (int i4 = t; i4 < 128 * 14; i4 += 256) {      // float4 staging loads
        int c = i4 / 14, w4 = (i4 - c * 14) * 4;
        float4 v = *(const float4*)(src + c * HW + w4);
        row[c * 57 + w4 + 0] = v.x;
        row[c * 57 + w4 + 1] = v.y;
        row[c * 57 + w4 + 2] = v.z;
        row[c * 57 + w4 + 3] = v.w;
    }
    __syncthreads();
    for (int i4 = t; i4 < 58 * 32; i4 += 256) {       // char4 per thread
        int wp = i4 >> 5;
        int c0 = (i4 & 31) * 4;
        char q[4] = {0, 0, 0, 0};
        if (wp >= 1 && wp <= 56) {
#pragma unroll
            for (int k = 0; k < 4; ++k) {
                int c = c0 + k;
                float xn = (row[c * 57 + wp - 1] - mean[c]) * rstd[c] * g[c] + b[c];
                q[k] = xn > 0.f ? 1 : (xn < 0.f ? -1 : 0);
            }
        }
        *(char4*)(o + wp * 128 + c0) = make_char4(q[0], q[1], q[2], q[3]);
    }
}

__global__ __launch_bounds__(256) void act2_kernel(const short* __restrict__ p1,
        const float* __restrict__ scale1, const float* __restrict__ a1ptr,
        const float* __restrict__ mean, const float* __restrict__ rstd,
        const float* __restrict__ g, const float* __restrict__ b,
        char* __restrict__ apad) {
    __shared__ float row[128 * 57];
    int blk = blockIdx.x;
    int n = blk / 58, hp = blk - n * 58;
    char* o = apad + (n * 58 + hp) * 58 * 128;
    int t = threadIdx.x;
    if (hp == 0 || hp == 57) {
        for (int i4 = t; i4 < 58 * 32; i4 += 256)
            *(char4*)(o + i4 * 4) = make_char4(0, 0, 0, 0);
        return;
    }
    float a1 = a1ptr[0];
    const short* src = p1 + n * HW + (hp - 1) * 56;   // + c*M_TOT + w
    for (int i8 = t; i8 < 128 * 7; i8 += 256) {       // short8 staging loads
        int c = i8 / 7, w8 = (i8 - c * 7) * 8;
        short8 v = *(const short8*)(src + (size_t)c * M_TOT + w8);
        float sc = scale1[c];
#pragma unroll
        for (int k = 0; k < 8; ++k) {
            float val = sc * (float)v[k];
            row[c * 57 + w8 + k] = val >= 0.f ? val : a1 * val;   // prelu1
        }
    }
    __syncthreads();
    for (int i4 = t; i4 < 58 * 32; i4 += 256) {
        int wp = i4 >> 5;
        int c0 = (i4 & 31) * 4;
        char q[4] = {0, 0, 0, 0};
        if (wp >= 1 && wp <= 56) {
#pragma unroll
            for (int k = 0; k < 4; ++k) {
                int c = c0 + k;
                float xn = (row[c * 57 + wp - 1] - mean[c]) * rstd[c] * g[c] + b[c];
                q[k] = xn > 0.f ? 1 : (xn < 0.f ? -1 : 0);
            }
        }
        *(char4*)(o + wp * 128 + c0) = make_char4(q[0], q[1], q[2], q[3]);
    }
}

// ---------------- implicit-GEMM binary conv (r14/r16-proven optimum), i8 MFMA ----------------
// Slab-resident B (6x58x128 XOR-swizzled, staged once), 9 full-tap steps, A 16KB/tap
// into 2-buf. One vmcnt+barrier per step. Per wave/step: 22 ds_read + 56 MFMA.
// obuf[cout][m] = raw int16 accumulator. Fused BN stats -> psumB/psqB[blk*128+c].
__global__ __launch_bounds__(256, 2) void conv_kernel(
        const char* __restrict__ apad,
        const char* __restrict__ wswz,
        const float* __restrict__ scale,
        const float* __restrict__ aptr,
        short* __restrict__ obuf,
        float* __restrict__ psumB,
        float* __restrict__ psqB) {
    // layout: slab [0, 44544) ; A 2-buf [44544, 44544 + 2*16384) = 77312 total
    __shared__ __align__(1024) char lds[SLABB + 2 * 16384];

    const int tid = threadIdx.x;
    const int lane = tid & 63;
    const int wid = tid >> 6;
    const int l15 = lane & 15;
    const int lq = lane >> 4;
    const int wr = wid >> 1;  // cout half
    const int wc = wid & 1;   // m half (112 m each)

    int bid = blockIdx.x;
    int mblk = (bid & 7) * 112 + (bid >> 3);   // XCD-contiguous (896 = 8*112)
    const int n = mblk / 14;
    const int hg = mblk - n * 14;
    const int m0 = n * HW + hg * 224;          // block's first output m

    const char* slabsrc = apad + (size_t)(n * 58 + hg * 4) * 58 * 128;
    char* slab = lds;
    char* Abuf = lds + SLABB;

    // ---- stage slab once: 11 instrs/thread, within-row XOR pre-swizzle (rule #21) ----
    {
#pragma unroll
        for (int i = 0; i < 11; ++i) {
            int gbyte = i * 4096 + tid * 16;
            if (i < 10 || gbyte < SLABB) {
                int r = gbyte >> 7;
                int cp = (gbyte >> 4) & 7;
                int wp = r % 58;
                gload_lds16(slabsrc + (gbyte & ~127) + ((cp ^ (wp & 7)) << 4),
                            slab + i * 4096 + wid * 1024);
            }
        }
    }

    // per-lane B-frag constants: mloc = wc*112 + mi*16 + l15 -> (ho, w)
    int Pm[7], Wm[7];
#pragma unroll
    for (int mi = 0; mi < 7; ++mi) {
        int mloc = wc * 112 + mi * 16 + l15;
        int ho = mloc / 56;
        int w = mloc - ho * 56;
        Pm[mi] = (ho * 58 + w) * 128;   // slab row base for dh=dw=0
        Wm[mi] = w;
    }

    // stage full tap t (16KB) into A-buffer buf: 4 gloads/thread
    auto stageA = [&](int t, int buf) {
        const char* wsrc = wswz + t * 16384 + tid * 16;
        char* dst = Abuf + buf * 16384 + wid * 1024;
#pragma unroll
        for (int i = 0; i < 4; ++i)
            gload_lds16(wsrc + i * 4096, dst + i * 4096);
    };

    i32x4 acc[4][7];
#pragma unroll
    for (int i = 0; i < 4; ++i)
#pragma unroll
        for (int j = 0; j < 7; ++j)
            acc[i][j] = (i32x4){0, 0, 0, 0};

    stageA(0, 0);   // in flight: slab(<=11) + A0(4)

    for (int t = 0; t < NTAP; ++t) {
        asm volatile("s_waitcnt vmcnt(0)" ::: "memory");
        __builtin_amdgcn_s_barrier();
        if (t + 1 < NTAP) stageA(t + 1, (t + 1) & 1);   // flies under this step's compute

        int dh = t / 3;
        int dw = t - dh * 3;
        int Q = (dh * 58 + dw) * 128;          // slab row offset for this tap
        const char* abuf = Abuf + (t & 1) * 16384;

#pragma unroll
        for (int ks = 0; ks < 2; ++ks) {
            i32x4 af[4], bf[7];
#pragma unroll
            for (int ci = 0; ci < 4; ++ci)
                af[ci] = *(const i32x4*)(abuf + ks * 8192 + (wr * 4 + ci) * 1024 + lane * 16);
            int c16 = ks * 4 + lq;
#pragma unroll
            for (int mi = 0; mi < 7; ++mi) {
                int wxd = (Wm[mi] + dw) & 7;
                bf[mi] = *(const i32x4*)(slab + Pm[mi] + Q + ((c16 ^ wxd) << 4));
            }
            __builtin_amdgcn_s_setprio(1);
#pragma unroll
            for (int ci = 0; ci < 4; ++ci)
#pragma unroll
                for (int mi = 0; mi < 7; ++mi)
                    acc[ci][mi] = __builtin_amdgcn_mfma_i32_16x16x64_i8(
                        af[ci], bf[mi], acc[ci][mi], 0, 0, 0);
            __builtin_amdgcn_s_setprio(0);
        }
    }

    // ---- epilogue: store raw int16 + fused per-channel stats of prelu(scale*acc) ----
    // partS/partQ live in A-buf1 region (last read t=7; barrier at t=8 separates;
    // step t=8 reads buf0 only — disjoint from these writes).
    float alpha = aptr[0];
    float* partS = (float*)(Abuf + 16384);   // [2 wc][128 cout]
    float* partQ = (float*)(Abuf + 16384 + 1024);
#pragma unroll
    for (int ci = 0; ci < 4; ++ci) {
        int cb = wr * 64 + ci * 16 + lq * 4;
#pragma unroll
        for (int r = 0; r < 4; ++r) {
            float sc = scale[cb + r];
            short* op = obuf + (size_t)(cb + r) * M_TOT + m0 + wc * 112 + l15;
            float s = 0.f, q = 0.f;
#pragma unroll
            for (int mi = 0; mi < 7; ++mi) {
                int iv = acc[ci][mi][r];
                float v = (float)iv * sc;
                float pv = v >= 0.f ? v : alpha * v;
                op[mi * 16] = (short)iv;
                s += pv; q += pv * pv;
            }
#pragma unroll
            for (int msk = 1; msk <= 8; msk <<= 1) {
                s += __shfl_xor(s, msk, 64);
                q += __shfl_xor(q, msk, 64);
            }
            if (l15 == 0) { partS[wc * 128 + cb + r] = s; partQ[wc * 128 + cb + r] = q; }
        }
    }
    __syncthreads();
    if (tid < 128) {
        psumB[bid * 128 + tid] = partS[tid] + partS[128 + tid];   // coalesced row
        psqB [bid * 128 + tid] = partQ[tid] + partQ[128 + tid];
    }
}

// ---------------- final: scale2+prelu2 + BN3 + residual + prelu3 ----------------
__global__ __launch_bounds__(256) void final_kernel(const short* __restrict__ p2,
        const float* __restrict__ scale2, const float* __restrict__ a2ptr,
        const float* __restrict__ x,
        const float* __restrict__ mean, const float* __restrict__ rstd,
        const float* __restrict__ g, const float* __restrict__ b,
        const float* __restrict__ a3ptr, float* __restrict__ out) {
    int bid = blockIdx.x;               // 8192
    int n = bid >> 7, c = bid & 127;
    float sc = scale2[c], a2 = a2ptr[0];
    float m = mean[c], r = rstd[c], gg = g[c], bb = b[c], a3 = a3ptr[0];
    const short* pp = p2 + (size_t)c * M_TOT + n * HW;
    const float* xx = x + (n * 128 + c) * HW;
    float* oo = out + (n * 128 + c) * HW;
    int t = threadIdx.x;
    for (int i8 = t; i8 < 392; i8 += 256) {     // 3136 = 392*8
        short8 v = *(const short8*)(pp + i8 * 8);
        float4 x0 = *(const float4*)(xx + i8 * 8);
        float4 x1 = *(const float4*)(xx + i8 * 8 + 4);
        float o[8];
#pragma unroll
        for (int k = 0; k < 8; ++k) {
            float pv = (float)v[k] * sc;
            pv = pv >= 0.f ? pv : a2 * pv;      // prelu2
            float xv = (k < 4) ? ((const float*)&x0)[k] : ((const float*)&x1)[k - 4];
            float val = (pv - m) * r * gg + bb + xv;
            o[k] = val >= 0.f ? val : a3 * val; // prelu3
        }
        *(float4*)(oo + i8 * 8)     = make_float4(o[0], o[1], o[2], o[3]);
        *(float4*)(oo + i8 * 8 + 4) = make_float4(o[4], o[5], o[6], o[7]);
    }
}

extern "C" void kernel_launch(void* const* d_in, const int* in_sizes, int n_in,
                              void* d_out, int out_size, void* d_ws, size_t ws_size,
                              hipStream_t stream) {
    const float* x  = (const float*)d_in[0];
    const float* g1 = (const float*)d_in[1];
    const float* b1 = (const float*)d_in[2];
    const float* w1 = (const float*)d_in[3];
    const float* a1 = (const float*)d_in[4];
    const float* g2 = (const float*)d_in[5];
    const float* b2 = (const float*)d_in[6];
    const float* w2 = (const float*)d_in[7];
    const float* a2 = (const float*)d_in[8];
    const float* g3 = (const float*)d_in[9];
    const float* b3 = (const float*)d_in[10];
    const float* a3 = (const float*)d_in[11];
    float* out = (float*)d_out;
    char* ws = (char*)d_ws;

    // Workspace map — end offsets computed as start + exact size:
    //   psum   4,096   + 32,768   = 36,864
    //   psq    36,864  + 32,768   = 69,632
    //   psumB  69,632  + 802,816  = 872,448      (region >= 896*128*4 = 458,752)
    //   psqB   872,448 + 802,816  = 1,675,264
    //   wswz1  1,675,264 + 147,456 = 1,822,720
    //   wswz2  1,822,720 + 147,456 = 1,970,176
    //   apad8  1,970,176 + 27,557,888 = 29,528,064   (64*58*58*128 bytes)
    //   buf2s  29,528,064 + 51,380,224 = 80,908,288  (2*128*200704)
    float* scale1 = (float*)(ws);
    float* scale2 = (float*)(ws + 512);
    float* mean1  = (float*)(ws + 1024);
    float* rstd1  = (float*)(ws + 1536);
    float* mean2  = (float*)(ws + 2048);
    float* rstd2  = (float*)(ws + 2560);
    float* mean3  = (float*)(ws + 3072);
    float* rstd3  = (float*)(ws + 3584);
    float* psum   = (float*)(ws + 4096);
    float* psq    = (float*)(ws + 36864);
    float* psumB  = (float*)(ws + 69632);
    float* psqB   = (float*)(ws + 872448);
    char* wswz1   = (char*)(ws + 1675264);
    char* wswz2   = (char*)(ws + 1822720);
    char* apad8   = (char*)(ws + 1970176);
    short* buf2s  = (short*)(ws + 29528064);
    short* buf1s  = (short*)out;              // alias d_out (51.4 of 103 MB)

    wscale_kernel<<<256, 256, 0, stream>>>(w1, w2, scale1, scale2);
    wsign_kernel<<<1152, 256, 0, stream>>>(w1, w2, wswz1, wswz2);

    stats_nchw_kernel<<<8192, 256, 0, stream>>>(x, psum, psq);
    finalize_kernel<<<1, 128, 0, stream>>>(psum, psq, 64, mean1, rstd1);
    act1_kernel<<<3712, 256, 0, stream>>>(x, mean1, rstd1, g1, b1, apad8);
    conv_kernel<<<NBLK, 256, 0, stream>>>(apad8, wswz1, scale1, a1, buf1s, psumB, psqB);

    finalizeB_kernel<<<128, 256, 0, stream>>>(psumB, psqB, mean2, rstd2);
    act2_kernel<<<3712, 256, 0, stream>>>(buf1s, scale1, a1, mean2, rstd2, g2, b2, apad8);
    conv_kernel<<<NBLK, 256, 0, stream>>>(apad8, wswz2, scale2, a2, buf2s, psumB, psqB);

    finalizeB_kernel<<<128, 256, 0, stream>>>(psumB, psqB, mean3, rstd3);
    final_kernel<<<8192, 256, 0, stream>>>(buf2s, scale2, a2, x, mean3, rstd3, g3, b3, a3, out);
}